// Round 1
// baseline (512.444 us; speedup 1.0000x reference)
//
#include <hip/hip_runtime.h>
#include <hip/hip_bf16.h>

#define BB 128
#define FF 12288
#define HH 2048
#define TAU_F 0.1f
#define THR_F 1e-3f

// ---------------------------------------------------------------------------
// Kernel 1: detect whether x0 is all-zero (it is, by construction, but stay
// general). Deterministic for fixed inputs.
__global__ void zdetect_kernel(const float4* __restrict__ x0, int n4,
                               int* __restrict__ flag) {
    int i = blockIdx.x * blockDim.x + threadIdx.x;
    bool nz = false;
    for (; i < n4; i += gridDim.x * blockDim.x) {
        float4 v = x0[i];
        nz |= (v.x != 0.f) | (v.y != 0.f) | (v.z != 0.f) | (v.w != 0.f);
    }
    if (nz) atomicOr(flag, 1);
}

// ---------------------------------------------------------------------------
// Kernel 2: split-K GEMM partials.  P[z*splitk + kc][b][h] = X_z[b, kchunk] @ W1[kchunk, h]
// z = 0: x,  z = 1: x0 (skipped -> zeros if *nzflag == 0).
// grid: (HH/64, splitk, 2), block 256.  Per-thread tile: 4 rows x 8 cols.
__global__ __launch_bounds__(256) void gemm_kernel(
    const float* __restrict__ x, const float* __restrict__ x0,
    const float* __restrict__ W1, float* __restrict__ P,
    const int* __restrict__ nzflag, int splitk, int kchunk) {
    const int ct = blockIdx.x;
    const int kc = blockIdx.y;
    const int z  = blockIdx.z;
    const int t  = threadIdx.x;
    const int cg = t & 7;        // 8 col groups
    const int rg = t >> 3;       // 32 row groups
    const int r0 = rg * 4;
    const int cc = ct * 64 + cg * 8;

    float acc[4][8];
#pragma unroll
    for (int i = 0; i < 4; ++i)
#pragma unroll
        for (int n = 0; n < 8; ++n) acc[i][n] = 0.f;

    const float* __restrict__ X = z ? x0 : x;
    const bool skip = (z == 1) && (*nzflag == 0);

    if (!skip) {
        const int k0 = kc * kchunk;
        const int k1 = k0 + kchunk;
        for (int k = k0; k < k1; k += 4) {
            float xr[4][4];
#pragma unroll
            for (int i = 0; i < 4; ++i) {
                float4 v = *(const float4*)(X + (size_t)(r0 + i) * FF + k);
                xr[i][0] = v.x; xr[i][1] = v.y; xr[i][2] = v.z; xr[i][3] = v.w;
            }
            float wr[4][8];
#pragma unroll
            for (int j = 0; j < 4; ++j) {
                float4 a = *(const float4*)(W1 + (size_t)(k + j) * HH + cc);
                float4 b = *(const float4*)(W1 + (size_t)(k + j) * HH + cc + 4);
                wr[j][0] = a.x; wr[j][1] = a.y; wr[j][2] = a.z; wr[j][3] = a.w;
                wr[j][4] = b.x; wr[j][5] = b.y; wr[j][6] = b.z; wr[j][7] = b.w;
            }
#pragma unroll
            for (int j = 0; j < 4; ++j)
#pragma unroll
                for (int i = 0; i < 4; ++i)
#pragma unroll
                    for (int n = 0; n < 8; ++n)
                        acc[i][n] = fmaf(xr[i][j], wr[j][n], acc[i][n]);
        }
    }

    float* __restrict__ Pp = P + (size_t)(z * splitk + kc) * BB * HH;
#pragma unroll
    for (int i = 0; i < 4; ++i) {
        float4 o0, o1;
        o0.x = acc[i][0]; o0.y = acc[i][1]; o0.z = acc[i][2]; o0.w = acc[i][3];
        o1.x = acc[i][4]; o1.y = acc[i][5]; o1.z = acc[i][6]; o1.w = acc[i][7];
        *(float4*)(Pp + (size_t)(r0 + i) * HH + cc) = o0;
        *(float4*)(Pp + (size_t)(r0 + i) * HH + cc + 4) = o1;
    }
}

// ---------------------------------------------------------------------------
// Kernel 3: deterministic split-K reduction + 30-step per-sample bisection.
// One wave (64 lanes) per sample; each lane owns 32 h-indices (stride 64).
__global__ __launch_bounds__(64) void bisect_kernel(
    const float* __restrict__ P, const float* __restrict__ w2,
    float* __restrict__ cdone, int splitk) {
    const int b = blockIdx.x;
    const int l = threadIdx.x;
    const size_t BH = (size_t)BB * HH;

    float u0[32], dd[32], wv[32];
#pragma unroll
    for (int j = 0; j < 32; ++j) {
        const int h = l + 64 * j;
        float s1 = 0.f, s0 = 0.f;
        for (int kc = 0; kc < splitk; ++kc) {          // fixed order: deterministic
            s1 += P[(size_t)kc * BH + (size_t)b * HH + h];
            s0 += P[(size_t)(splitk + kc) * BH + (size_t)b * HH + h];
        }
        u0[j] = s0;
        dd[j] = s1 - s0;
        wv[j] = w2[h];
    }

    auto feval = [&](float c) -> float {
        float s = 0.f;
#pragma unroll
        for (int j = 0; j < 32; ++j)
            s = fmaf(fmaxf(fmaf(c, dd[j], u0[j]), 0.f), wv[j], s);
#pragma unroll
        for (int off = 32; off > 0; off >>= 1) s += __shfl_xor(s, off);
        return s - TAU_F;
    };

    const float f1 = feval(1.0f);
    const bool inside = (f1 <= 0.f);
    float a = 0.f, bh = 1.f, c = 1.f;
    bool done = inside;
    for (int it = 0; it < 30; ++it) {
        const float cm = 0.5f * (a + bh);
        const float v = feval(cm);
        const bool upd  = !done;
        const bool hit  = upd && (v >= -THR_F) && (v < 0.f);
        const bool go_a = upd && (v < 0.f) && !hit;
        const bool go_b = upd && (v >= 0.f);
        a  = go_a ? cm : a;
        bh = go_b ? cm : bh;
        c  = upd  ? cm : c;
        done = done || hit;
    }

    if (l == 0) {
        cdone[b]      = c;
        cdone[BB + b] = done ? 1.f : 0.f;
    }
}

// ---------------------------------------------------------------------------
// Kernel 4: write output: proj = x0 + c*(x - x0) where done, NaN otherwise.
__global__ void writeout_kernel(const float* __restrict__ x0,
                                const float* __restrict__ x,
                                const float* __restrict__ cdone,
                                float* __restrict__ out) {
    const int n4 = BB * FF / 4;
    const int rowq = FF / 4;
    const float nanv = __int_as_float(0x7fc00000);
    int i = blockIdx.x * blockDim.x + threadIdx.x;
    for (; i < n4; i += gridDim.x * blockDim.x) {
        const int b = i / rowq;
        const float c = cdone[b];
        const bool dn = (cdone[BB + b] != 0.f);
        float4 xv  = ((const float4*)x)[i];
        float4 x0v = ((const float4*)x0)[i];
        float4 o;
        if (dn) {
            o.x = fmaf(c, xv.x - x0v.x, x0v.x);
            o.y = fmaf(c, xv.y - x0v.y, x0v.y);
            o.z = fmaf(c, xv.z - x0v.z, x0v.z);
            o.w = fmaf(c, xv.w - x0v.w, x0v.w);
        } else {
            o.x = o.y = o.z = o.w = nanv;
        }
        ((float4*)out)[i] = o;
    }
}

// ---------------------------------------------------------------------------
extern "C" void kernel_launch(void* const* d_in, const int* in_sizes, int n_in,
                              void* d_out, int out_size, void* d_ws, size_t ws_size,
                              hipStream_t stream) {
    const float* x0 = (const float*)d_in[0];
    const float* x  = (const float*)d_in[1];
    const float* W1 = (const float*)d_in[2];
    const float* w2 = (const float*)d_in[3];
    float* out = (float*)d_out;

    // ws layout: P[2*splitk][B][H] f32 | cdone[2*B] f32 | flag int
    const size_t need8 = (size_t)2 * 8 * BB * HH * sizeof(float) + 2 * BB * sizeof(float) + 64;
    const int splitk = (ws_size >= need8) ? 8 : 1;
    const int kchunk = FF / splitk;

    float* P = (float*)d_ws;
    float* cdone = P + (size_t)2 * splitk * BB * HH;
    int* flag = (int*)(cdone + 2 * BB);

    hipMemsetAsync(flag, 0, sizeof(int), stream);
    zdetect_kernel<<<256, 256, 0, stream>>>((const float4*)x0, BB * FF / 4, flag);

    dim3 g(HH / 64, splitk, 2);
    gemm_kernel<<<g, 256, 0, stream>>>(x, x0, W1, P, flag, splitk, kchunk);

    bisect_kernel<<<BB, 64, 0, stream>>>(P, w2, cdone, splitk);

    writeout_kernel<<<768, 256, 0, stream>>>(x0, x, cdone, out);
}

// Round 2
// 71.572 us; speedup vs baseline: 7.1598x; 7.1598x over previous
//
#include <hip/hip_runtime.h>
#include <hip/hip_bf16.h>

#define BB 128
#define FF 12288
#define HH 2048
#define TAU_F 0.1f
#define THR_F 1e-3f
#define NKG (FF / 8)          // 1536 k-groups of 8
#define BH (BB * HH)          // 262144

typedef __attribute__((ext_vector_type(4))) float f32x4;
typedef __attribute__((ext_vector_type(8))) short s16x8;
typedef __attribute__((ext_vector_type(8))) unsigned short u16x8;

#define AS1 __attribute__((address_space(1)))
#define AS3 __attribute__((address_space(3)))

// Round-to-nearest-even bf16 split: v ~= hi + lo with both bf16.
__device__ __forceinline__ void bsplit(float v, unsigned short& h, unsigned short& l) {
    unsigned int u  = __float_as_uint(v);
    unsigned int rh = (u + 0x7fffu + ((u >> 16) & 1u)) >> 16;
    float hf = __uint_as_float(rh << 16);
    float lf = v - hf;
    unsigned int ul = __float_as_uint(lf);
    unsigned int rl = (ul + 0x7fffu + ((ul >> 16) & 1u)) >> 16;
    h = (unsigned short)rh;
    l = (unsigned short)rl;
}

// ---------------------------------------------------------------------------
// x0 == 0 detector (deterministic).
__global__ void zdetect_kernel(const float4* __restrict__ x0, int n4,
                               int* __restrict__ flag) {
    int i = blockIdx.x * blockDim.x + threadIdx.x;
    bool nz = false;
    for (; i < n4; i += gridDim.x * blockDim.x) {
        float4 v = x0[i];
        nz |= (v.x != 0.f) | (v.y != 0.f) | (v.z != 0.f) | (v.w != 0.f);
    }
    if (nz) atomicOr(flag, 1);
}

// ---------------------------------------------------------------------------
// Pre-split x (and x0 if nonzero) into packed bf16 hi/lo, fragment-order
// layout: A*[z][kg][m][8] (16B per (kg,m) chunk) -> enables global_load_lds.
__global__ __launch_bounds__(256) void presplit_kernel(
    const float* __restrict__ x, const float* __restrict__ x0,
    unsigned short* __restrict__ Ah, unsigned short* __restrict__ Al,
    const int* __restrict__ flag) {
    const int z = blockIdx.y;
    if (z == 1 && *flag == 0) return;
    const float* __restrict__ X = z ? x0 : x;
    unsigned short* AH = Ah + (size_t)z * NKG * BB * 8;
    unsigned short* AL = Al + (size_t)z * NKG * BB * 8;
    const int t = threadIdx.x;
    const int kg = blockIdx.x * 8 + (t & 7);
#pragma unroll
    for (int r = 0; r < 4; ++r) {
        const int m = (t >> 3) + r * 32;
        const float* src = X + (size_t)m * FF + kg * 8;
        u16x8 hv, lv;
#pragma unroll
        for (int j = 0; j < 8; ++j) {
            unsigned short h, lo;
            bsplit(src[j], h, lo);
            hv[j] = h; lv[j] = lo;
        }
        const size_t o = ((size_t)kg * BB + m) * 8;
        *(u16x8*)(AH + o) = hv;
        *(u16x8*)(AL + o) = lv;
    }
}

// ---------------------------------------------------------------------------
// Split-precision MFMA GEMM: U[z] (or P partials) = X_z @ W1.
// Tile 128x64, BK=32, double-buffered LDS, splitK across blocks.
// LDS per buffer (ushort units): Ah[4][128][8]=4096, Al: +4096,
// Bh[4][64][8]: +2048 at 8192, Bl: +2048 at 10240 -> 12288 (24 KB).
__global__ __launch_bounds__(256, 3) void mfma_gemm_kernel(
    const unsigned short* __restrict__ Ah, const unsigned short* __restrict__ Al,
    const float* __restrict__ W1, float* __restrict__ P, float* __restrict__ U,
    const int* __restrict__ nzflag, int SK, int KC, int NIT) {
    const int z = blockIdx.y;
    if (z == 1 && *nzflag == 0) return;

    // XCD-aware bijective swizzle (gridDim.x always % 8 == 0 here).
    const int nwg = gridDim.x;
    const int bx  = blockIdx.x;
    const int wg  = (bx & 7) * (nwg >> 3) + (bx >> 3);
    const int ct  = wg & 31;   // column tile (64 cols)
    const int kc  = wg >> 5;   // split-K chunk

    const int t   = threadIdx.x;
    const int w   = t >> 6;    // wave 0..3
    const int l   = t & 63;
    const int kgl = l >> 4;    // frag k-group 0..3
    const int li  = l & 15;

    __shared__ unsigned short lds[2][12288];

    const size_t zoffA = (size_t)z * NKG * BB * 8;
    const unsigned short* APH = Ah + zoffA;
    const unsigned short* APL = Al + zoffA;

    f32x4 acc[2][4];
#pragma unroll
    for (int mt = 0; mt < 2; ++mt)
#pragma unroll
        for (int nt = 0; nt < 4; ++nt) acc[mt][nt] = (f32x4)0.f;

    const int kbase = kc * KC;
    const int bkg = t >> 6;    // B staging: k-subgroup of 8
    const int bn  = t & 63;    // B staging: column within tile

    auto stageB_load = [&](int it, float* v) {
        const float* src = W1 + (size_t)(kbase + it * 32 + bkg * 8) * HH + ct * 64 + bn;
#pragma unroll
        for (int j = 0; j < 8; ++j) v[j] = src[(size_t)j * HH];
    };
    auto stageB_write = [&](int buf, const float* v) {
        u16x8 hv, lv;
#pragma unroll
        for (int j = 0; j < 8; ++j) {
            unsigned short h, lo;
            bsplit(v[j], h, lo);
            hv[j] = h; lv[j] = lo;
        }
        unsigned short* d = &lds[buf][(bkg * 64 + bn) * 8];
        *(u16x8*)(d + 8192)  = hv;
        *(u16x8*)(d + 10240) = lv;
    };
    auto stageA = [&](int it, int buf) {
        const int kg0 = (kbase + it * 32) >> 3;
#pragma unroll
        for (int s = 0; s < 4; ++s) {
            const int slot = w * 4 + s;      // 16 slots: 8 hi then 8 lo
            const int isLo = slot >> 3;
            const int sl   = slot & 7;
            const int kgq  = sl >> 1;
            const int mh   = sl & 1;
            const unsigned short* src = (isLo ? APL : APH)
                + ((size_t)(kg0 + kgq) * BB + mh * 64 + l) * 8;
            unsigned short* dst = &lds[buf][isLo * 4096 + (kgq * 128 + mh * 64) * 8];
            __builtin_amdgcn_global_load_lds((const AS1 void*)src, (AS3 void*)dst, 16, 0, 0);
        }
    };
    auto compute = [&](int buf) {
        const unsigned short* L = lds[buf];
        s16x8 fah[2], fal[2], fbh[4], fbl[4];
#pragma unroll
        for (int mt = 0; mt < 2; ++mt) {
            const int mo = (kgl * 128 + w * 32 + mt * 16 + li) * 8;
            fah[mt] = *(const s16x8*)&L[mo];
            fal[mt] = *(const s16x8*)&L[4096 + mo];
        }
#pragma unroll
        for (int nt = 0; nt < 4; ++nt) {
            const int no = (kgl * 64 + nt * 16 + li) * 8;
            fbh[nt] = *(const s16x8*)&L[8192 + no];
            fbl[nt] = *(const s16x8*)&L[10240 + no];
        }
#pragma unroll
        for (int mt = 0; mt < 2; ++mt)
#pragma unroll
            for (int nt = 0; nt < 4; ++nt) {
                acc[mt][nt] = __builtin_amdgcn_mfma_f32_16x16x32_bf16(fah[mt], fbh[nt], acc[mt][nt], 0, 0, 0);
                acc[mt][nt] = __builtin_amdgcn_mfma_f32_16x16x32_bf16(fah[mt], fbl[nt], acc[mt][nt], 0, 0, 0);
                acc[mt][nt] = __builtin_amdgcn_mfma_f32_16x16x32_bf16(fal[mt], fbh[nt], acc[mt][nt], 0, 0, 0);
            }
    };

    // Prologue: stage iter 0 into buffer 0.
    float bv[8];
    stageB_load(0, bv);
    stageA(0, 0);
    stageB_write(0, bv);
    __syncthreads();

    for (int it = 0; it < NIT; ++it) {
        const int cur = it & 1;
        const bool more = (it + 1 < NIT);
        float bnx[8];
        if (more) { stageB_load(it + 1, bnx); stageA(it + 1, cur ^ 1); }
        compute(cur);
        if (more) stageB_write(cur ^ 1, bnx);
        __syncthreads();
    }

    float* dst = (SK == 1) ? (U + (size_t)z * BH) : (P + (size_t)(z * SK + kc) * BH);
    const int r0 = w * 32 + (l >> 4) * 4;
    const int c0 = ct * 64 + li;
#pragma unroll
    for (int mt = 0; mt < 2; ++mt)
#pragma unroll
        for (int nt = 0; nt < 4; ++nt)
#pragma unroll
            for (int r = 0; r < 4; ++r)
                dst[(size_t)(r0 + mt * 16 + r) * HH + c0 + nt * 16] = acc[mt][nt][r];
}

// ---------------------------------------------------------------------------
// Deterministic fixed-order split-K reduction: U[z] = sum_kc P[z][kc].
__global__ __launch_bounds__(256) void reduce_kernel(
    const float* __restrict__ P, float* __restrict__ U,
    const int* __restrict__ flag, int SK) {
    const int z = blockIdx.y;
    const int idx = blockIdx.x * 256 + threadIdx.x;
    if (z == 1 && *flag == 0) { U[BH + idx] = 0.f; return; }
    if (SK == 1) return;  // gemm wrote U directly
    float s = 0.f;
    for (int kc = 0; kc < SK; ++kc) s += P[(size_t)(z * SK + kc) * BH + idx];
    U[(size_t)z * BH + idx] = s;
}

// ---------------------------------------------------------------------------
// Legacy fp32 fallback GEMM (only if ws is tiny). Writes U layout directly.
__global__ __launch_bounds__(256) void legacy_gemm_kernel(
    const float* __restrict__ x, const float* __restrict__ x0,
    const float* __restrict__ W1, float* __restrict__ P,
    const int* __restrict__ nzflag) {
    const int ct = blockIdx.x, z = blockIdx.z, t = threadIdx.x;
    const int cg = t & 7, rg = t >> 3;
    const int r0 = rg * 4, cc = ct * 64 + cg * 8;
    float acc[4][8];
#pragma unroll
    for (int i = 0; i < 4; ++i)
#pragma unroll
        for (int n = 0; n < 8; ++n) acc[i][n] = 0.f;
    const float* __restrict__ X = z ? x0 : x;
    const bool skip = (z == 1) && (*nzflag == 0);
    if (!skip) {
        for (int k = 0; k < FF; k += 4) {
            float xr[4][4];
#pragma unroll
            for (int i = 0; i < 4; ++i) {
                float4 v = *(const float4*)(X + (size_t)(r0 + i) * FF + k);
                xr[i][0] = v.x; xr[i][1] = v.y; xr[i][2] = v.z; xr[i][3] = v.w;
            }
            float wr[4][8];
#pragma unroll
            for (int j = 0; j < 4; ++j) {
                float4 a = *(const float4*)(W1 + (size_t)(k + j) * HH + cc);
                float4 b = *(const float4*)(W1 + (size_t)(k + j) * HH + cc + 4);
                wr[j][0] = a.x; wr[j][1] = a.y; wr[j][2] = a.z; wr[j][3] = a.w;
                wr[j][4] = b.x; wr[j][5] = b.y; wr[j][6] = b.z; wr[j][7] = b.w;
            }
#pragma unroll
            for (int j = 0; j < 4; ++j)
#pragma unroll
                for (int i = 0; i < 4; ++i)
#pragma unroll
                    for (int n = 0; n < 8; ++n)
                        acc[i][n] = fmaf(xr[i][j], wr[j][n], acc[i][n]);
        }
    }
    float* Pp = P + (size_t)z * BH;
#pragma unroll
    for (int i = 0; i < 4; ++i) {
        float4 o0, o1;
        o0.x = acc[i][0]; o0.y = acc[i][1]; o0.z = acc[i][2]; o0.w = acc[i][3];
        o1.x = acc[i][4]; o1.y = acc[i][5]; o1.z = acc[i][6]; o1.w = acc[i][7];
        *(float4*)(Pp + (size_t)(r0 + i) * HH + cc) = o0;
        *(float4*)(Pp + (size_t)(r0 + i) * HH + cc + 4) = o1;
    }
}

// ---------------------------------------------------------------------------
// 30-step per-sample bisection on U0/U1 (one wave per sample).
__global__ __launch_bounds__(64) void bisect_kernel(
    const float* __restrict__ U, const float* __restrict__ w2,
    float* __restrict__ cdone) {
    const int b = blockIdx.x;
    const int l = threadIdx.x;
    float u0[32], dd[32], wv[32];
#pragma unroll
    for (int j = 0; j < 32; ++j) {
        const int h = l + 64 * j;
        const float s1 = U[(size_t)b * HH + h];
        const float s0 = U[BH + (size_t)b * HH + h];
        u0[j] = s0; dd[j] = s1 - s0; wv[j] = w2[h];
    }
    auto feval = [&](float c) -> float {
        float s = 0.f;
#pragma unroll
        for (int j = 0; j < 32; ++j)
            s = fmaf(fmaxf(fmaf(c, dd[j], u0[j]), 0.f), wv[j], s);
#pragma unroll
        for (int off = 32; off > 0; off >>= 1) s += __shfl_xor(s, off);
        return s - TAU_F;
    };
    const float f1 = feval(1.0f);
    const bool inside = (f1 <= 0.f);
    float a = 0.f, bh = 1.f, c = 1.f;
    bool done = inside;
    for (int it = 0; it < 30; ++it) {
        const float cm = 0.5f * (a + bh);
        const float v = feval(cm);
        const bool upd  = !done;
        const bool hit  = upd && (v >= -THR_F) && (v < 0.f);
        const bool go_a = upd && (v < 0.f) && !hit;
        const bool go_b = upd && (v >= 0.f);
        a  = go_a ? cm : a;
        bh = go_b ? cm : bh;
        c  = upd  ? cm : c;
        done = done || hit;
    }
    if (l == 0) {
        cdone[b]      = c;
        cdone[BB + b] = done ? 1.f : 0.f;
    }
}

// ---------------------------------------------------------------------------
__global__ void writeout_kernel(const float* __restrict__ x0,
                                const float* __restrict__ x,
                                const float* __restrict__ cdone,
                                float* __restrict__ out) {
    const int n4 = BB * FF / 4;
    const int rowq = FF / 4;
    const float nanv = __int_as_float(0x7fc00000);
    int i = blockIdx.x * blockDim.x + threadIdx.x;
    for (; i < n4; i += gridDim.x * blockDim.x) {
        const int b = i / rowq;
        const float c = cdone[b];
        const bool dn = (cdone[BB + b] != 0.f);
        float4 xv  = ((const float4*)x)[i];
        float4 x0v = ((const float4*)x0)[i];
        float4 o;
        if (dn) {
            o.x = fmaf(c, xv.x - x0v.x, x0v.x);
            o.y = fmaf(c, xv.y - x0v.y, x0v.y);
            o.z = fmaf(c, xv.z - x0v.z, x0v.z);
            o.w = fmaf(c, xv.w - x0v.w, x0v.w);
        } else {
            o.x = o.y = o.z = o.w = nanv;
        }
        ((float4*)out)[i] = o;
    }
}

// ---------------------------------------------------------------------------
extern "C" void kernel_launch(void* const* d_in, const int* in_sizes, int n_in,
                              void* d_out, int out_size, void* d_ws, size_t ws_size,
                              hipStream_t stream) {
    const float* x0 = (const float*)d_in[0];
    const float* x  = (const float*)d_in[1];
    const float* W1 = (const float*)d_in[2];
    const float* w2 = (const float*)d_in[3];
    float* out = (float*)d_out;
    char* ws = (char*)d_ws;

    // ws layout: Ah | Al | U[2][B][H] | cdone[256] | flag | P[2][SK][B][H]
    const size_t szA   = (size_t)2 * NKG * BB * 8 * sizeof(unsigned short); // 6291456
    const size_t offAh = 0;
    const size_t offAl = szA;
    const size_t offU  = 2 * szA;
    const size_t offCd = offU + (size_t)2 * BH * sizeof(float);
    const size_t offFl = offCd + 1024;
    const size_t offP  = offFl + 64;

    int SK = 0;
    const int cand[5] = {24, 12, 6, 3, 1};
    for (int i = 0; i < 5; ++i) {
        const size_t need = offP + (size_t)2 * cand[i] * BH * sizeof(float);
        if (ws_size >= need) { SK = cand[i]; break; }
    }

    if (SK > 0) {
        unsigned short* Ah = (unsigned short*)(ws + offAh);
        unsigned short* Al = (unsigned short*)(ws + offAl);
        float* U     = (float*)(ws + offU);
        float* cdone = (float*)(ws + offCd);
        int*   flag  = (int*)(ws + offFl);
        float* P     = (float*)(ws + offP);
        const int KC = FF / SK, NIT = KC / 32;

        hipMemsetAsync(flag, 0, sizeof(int), stream);
        zdetect_kernel<<<256, 256, 0, stream>>>((const float4*)x0, BB * FF / 4, flag);
        presplit_kernel<<<dim3(NKG / 8, 2), 256, 0, stream>>>(x, x0, Ah, Al, flag);
        mfma_gemm_kernel<<<dim3(32 * SK, 2), 256, 0, stream>>>(Ah, Al, W1, P, U, flag, SK, KC, NIT);
        reduce_kernel<<<dim3(BH / 256, 2), 256, 0, stream>>>(P, U, flag, SK);
        bisect_kernel<<<BB, 64, 0, stream>>>(U, w2, cdone);
        writeout_kernel<<<768, 256, 0, stream>>>(x0, x, cdone, out);
    } else {
        // Low-memory fallback: fp32 VALU GEMM straight into U.
        float* U     = (float*)ws;
        float* cdone = (float*)(ws + (size_t)2 * BH * sizeof(float));
        int*   flag  = (int*)(ws + (size_t)2 * BH * sizeof(float) + 1024);
        hipMemsetAsync(flag, 0, sizeof(int), stream);
        zdetect_kernel<<<256, 256, 0, stream>>>((const float4*)x0, BB * FF / 4, flag);
        legacy_gemm_kernel<<<dim3(32, 1, 2), 256, 0, stream>>>(x, x0, W1, U, flag);
        bisect_kernel<<<BB, 64, 0, stream>>>(U, w2, cdone);
        writeout_kernel<<<768, 256, 0, stream>>>(x0, x, cdone, out);
    }
}